// Round 8
// baseline (601.636 us; speedup 1.0000x reference)
//
#include <hip/hip_runtime.h>
#include <math.h>

#define BATCH 4096
#define D 784
#define N 10000

#define KP 800                 // padded K (halves)
#define NPAD 10240             // 40 * 256
#define GX2 40
#define GY2 16
#define MARGIN 3.0f

typedef __attribute__((ext_vector_type(8))) short bh8;
typedef __attribute__((ext_vector_type(4))) float fx4;
typedef const __attribute__((address_space(1))) void CGV;
typedef __attribute__((address_space(3))) void LDSV;

static __device__ __forceinline__ unsigned short f2bf(float f) {
    unsigned u = __float_as_uint(f);
    unsigned r = u + 0x7fffu + ((u >> 16) & 1u);
    return (unsigned short)(r >> 16);
}

static __device__ __forceinline__ void top2_insert(float w, int j, float& v0, int& i0,
                                                   float& v1, int& i1) {
    if (w < v0 || (w == v0 && j < i0)) { v1 = v0; i1 = i0; v0 = w; i0 = j; }
    else if (w < v1 || (w == v1 && j < i1)) { v1 = w; i1 = j; }
}

// ---------------------------------------------------------------------------
__global__ __launch_bounds__(256) void convert_x_kernel(const float* __restrict__ x,
                                                        unsigned short* __restrict__ xh) {
    int row = blockIdx.x;
    const float4* xr = (const float4*)(x + (size_t)row * D);
    unsigned short* dst = xh + (size_t)row * KP;
    for (int i = threadIdx.x; i < KP / 4; i += 256) {
        int k = i * 4;
        uint2 o;
        if (k < D) {
            float4 v = xr[i];
            o.x = (unsigned)f2bf(v.x) | ((unsigned)f2bf(v.y) << 16);
            o.y = (unsigned)f2bf(v.z) | ((unsigned)f2bf(v.w) << 16);
        } else { o.x = 0u; o.y = 0u; }
        *(uint2*)(dst + k) = o;
    }
}

__global__ __launch_bounds__(256) void convert_w_kernel(const float* __restrict__ w,
                                                        unsigned short* __restrict__ wh,
                                                        float* __restrict__ wsq) {
    int row = blockIdx.x;
    unsigned short* dst = wh + (size_t)row * KP;
    float s = 0.f;
    if (row < N) {
        const float4* wr = (const float4*)(w + (size_t)row * D);
        for (int i = threadIdx.x; i < KP / 4; i += 256) {
            int k = i * 4;
            uint2 o;
            if (k < D) {
                float4 v = wr[i];
                s += v.x * v.x + v.y * v.y + v.z * v.z + v.w * v.w;
                o.x = (unsigned)f2bf(v.x) | ((unsigned)f2bf(v.y) << 16);
                o.y = (unsigned)f2bf(v.z) | ((unsigned)f2bf(v.w) << 16);
            } else { o.x = 0u; o.y = 0u; }
            *(uint2*)(dst + k) = o;
        }
    } else {
        for (int i = threadIdx.x; i < KP / 4; i += 256) {
            uint2 o; o.x = 0u; o.y = 0u;
            *(uint2*)(dst + i * 4) = o;
        }
    }
    __shared__ float sred[4];
    #pragma unroll
    for (int off = 32; off; off >>= 1) s += __shfl_down(s, off);
    if ((threadIdx.x & 63) == 0) sred[threadIdx.x >> 6] = s;
    __syncthreads();
    if (threadIdx.x == 0) {
        float t = sred[0] + sred[1] + sred[2] + sred[3];
        wsq[row] = (row < N) ? t : INFINITY;
    }
}

// ---------------------------------------------------------------------------
// 256x256 / BK=64 MFMA distance kernel with the correct counted-vmcnt ledger:
// per tile: stage(next, other buf) -> vmcnt(8)  [waits only for data staged a
// FULL TILE earlier -> ~free] -> barrier -> 64 MFMA/wave -> barrier.
// 13 tiles (12 full + clamped-source tail). 8 waves (2M x 4N).
// ---------------------------------------------------------------------------
__global__ __launch_bounds__(512, 2) void dist_mfma256_kernel(
    const unsigned short* __restrict__ xh, const unsigned short* __restrict__ wh,
    const float* __restrict__ wsq, float4* __restrict__ partial) {
    __shared__ __align__(16) char smem[131072];   // buf b: A @ b*65536, B @ +32768

    const int tid = threadIdx.x;
    const int lane = tid & 63;
    const int wid = tid >> 6;            // 0..7
    const int waveM = (wid >> 2) * 128;
    const int wn = wid & 3;
    const int waveN = wn * 64;

    // XCD remap (worked in r7: FETCH 81 MB): XCD owns 2 row-panels, sweeps bx
    const int L = blockIdx.x + GX2 * blockIdx.y;
    const int xcd = L & 7;
    const int sg = L >> 3;
    const int bx = sg >> 1;              // 0..39
    const int by = xcd * 2 + (sg & 1);   // 0..15
    const int rowBase = by * 256;
    const int colBase = bx * 256;

    // staging: lane i of wave w, call j -> row w*32 + j*8 + (i>>3),
    // phys seg i&7 holds logical seg ls = (i&7) ^ (row&7)
    const int srow = (tid >> 6) * 32 + ((tid >> 3) & 7);   // + j*8
    const int ls = (tid & 7) ^ ((tid >> 3) & 7);
    const int lsc = (ls < 4) ? ls : 3;   // tail clamp (garbage in logical>=4)

    const unsigned short* aB[4];
    const unsigned short* bB[4];
    const unsigned short* aT[4];
    const unsigned short* bT[4];
    #pragma unroll
    for (int j = 0; j < 4; j++) {
        aB[j] = xh + (size_t)(rowBase + srow + j * 8) * KP + ls * 8;
        bB[j] = wh + (size_t)(colBase + srow + j * 8) * KP + ls * 8;
        aT[j] = xh + (size_t)(rowBase + srow + j * 8) * KP + 768 + lsc * 8;
        bT[j] = wh + (size_t)(colBase + srow + j * 8) * KP + 768 + lsc * 8;
    }

    // fragment read byte-offsets within a buffer (A at +0, B at +32768)
    int offA[8][2], offB[4][2];
    #pragma unroll
    for (int m = 0; m < 8; m++) {
        int row = waveM + m * 16 + (lane & 15);
        #pragma unroll
        for (int ks = 0; ks < 2; ks++)
            offA[m][ks] = row * 128 + (((ks * 4 + (lane >> 4)) ^ (row & 7)) << 4);
    }
    #pragma unroll
    for (int n = 0; n < 4; n++) {
        int row = waveN + n * 16 + (lane & 15);
        #pragma unroll
        for (int ks = 0; ks < 2; ks++)
            offB[n][ks] = 32768 + row * 128 + (((ks * 4 + (lane >> 4)) ^ (row & 7)) << 4);
    }

    fx4 acc[8][4];
    #pragma unroll
    for (int m = 0; m < 8; m++)
        #pragma unroll
        for (int n = 0; n < 4; n++) acc[m][n] = (fx4)0.f;

    char* const ldsAw = smem + wid * 4096;           // + sel*65536 + j*1024
    char* const ldsBw = smem + 32768 + wid * 4096;

#define STAGE_N(sel, kt)                                                               \
    do {                                                                               \
        _Pragma("unroll")                                                              \
        for (int j = 0; j < 4; j++) {                                                  \
            __builtin_amdgcn_global_load_lds((CGV*)(aB[j] + (kt) * 64),                \
                (LDSV*)(ldsAw + (sel) * 65536 + j * 1024), 16, 0, 0);                  \
            __builtin_amdgcn_global_load_lds((CGV*)(bB[j] + (kt) * 64),                \
                (LDSV*)(ldsBw + (sel) * 65536 + j * 1024), 16, 0, 0);                  \
        }                                                                              \
    } while (0)

#define STAGE_T(sel)                                                                   \
    do {                                                                               \
        _Pragma("unroll")                                                              \
        for (int j = 0; j < 4; j++) {                                                  \
            __builtin_amdgcn_global_load_lds((CGV*)(aT[j]),                            \
                (LDSV*)(ldsAw + (sel) * 65536 + j * 1024), 16, 0, 0);                  \
            __builtin_amdgcn_global_load_lds((CGV*)(bT[j]),                            \
                (LDSV*)(ldsBw + (sel) * 65536 + j * 1024), 16, 0, 0);                  \
        }                                                                              \
    } while (0)

    // prologue: tile 0 into buf 0; full drain once
    STAGE_N(0, 0);
    asm volatile("s_waitcnt vmcnt(0)" ::: "memory");
    __builtin_amdgcn_s_barrier();

    int cb = 0;
    #pragma unroll 1
    for (int t = 0; t < 13; ++t) {
        if (t < 12) {
            if (t + 1 < 12) STAGE_N(cb ^ 1, t + 1);
            else            STAGE_T(cb ^ 1);
            // FIFO vmcnt: <=8 outstanding => tile t's 8 loads (issued a full
            // tile ago) have all landed; tile t+1's 8 keep flying.
            asm volatile("s_waitcnt vmcnt(8)" ::: "memory");
        } else {
            asm volatile("s_waitcnt vmcnt(0)" ::: "memory");
        }
        __builtin_amdgcn_s_barrier();
        __builtin_amdgcn_sched_barrier(0);   // no ds_read hoist above barrier

        const char* Ab = smem + cb * 65536;
        const int nks = (t < 12) ? 2 : 1;    // tail tile: k 768..799 only
        bh8 bfr[4][2];
        #pragma unroll
        for (int n = 0; n < 4; n++)
            #pragma unroll
            for (int ks = 0; ks < 2; ks++)
                if (ks < nks) bfr[n][ks] = *(const bh8*)(Ab + offB[n][ks]);
        __builtin_amdgcn_s_setprio(1);
        #pragma unroll
        for (int m = 0; m < 8; m++) {
            bh8 a0 = *(const bh8*)(Ab + offA[m][0]);
            #pragma unroll
            for (int n = 0; n < 4; n++)
                acc[m][n] = __builtin_amdgcn_mfma_f32_16x16x32_bf16(a0, bfr[n][0],
                                                                    acc[m][n], 0, 0, 0);
            if (nks == 2) {
                bh8 a1 = *(const bh8*)(Ab + offA[m][1]);
                #pragma unroll
                for (int n = 0; n < 4; n++)
                    acc[m][n] = __builtin_amdgcn_mfma_f32_16x16x32_bf16(a1, bfr[n][1],
                                                                        acc[m][n], 0, 0, 0);
            }
        }
        __builtin_amdgcn_s_setprio(0);
        __builtin_amdgcn_s_barrier();        // all reads of buf cb done
        cb ^= 1;
    }
#undef STAGE_N
#undef STAGE_T

    __syncthreads();   // before red aliases smem

    // ---- fold: per-row top-2 over this block's 256 cols (r7-proven) ----
    float4* red4 = (float4*)smem;
    const int colT = colBase + waveN + (lane & 15);
    float wq[4]; int ci[4];
    #pragma unroll
    for (int n = 0; n < 4; n++) { ci[n] = colT + n * 16; wq[n] = wsq[ci[n]]; }

    #pragma unroll
    for (int m = 0; m < 8; m++) {
        #pragma unroll
        for (int r = 0; r < 4; r++) {
            float v0 = INFINITY, v1 = INFINITY;
            int i0 = 0x7fffffff, i1 = 0x7fffffff;
            #pragma unroll
            for (int n = 0; n < 4; n++) {
                float dv = wq[n] - 2.f * acc[m][n][r];
                top2_insert(dv, ci[n], v0, i0, v1, i1);
            }
            #pragma unroll
            for (int mask = 1; mask < 16; mask <<= 1) {
                float w0 = __shfl_xor(v0, mask); int j0 = __shfl_xor(i0, mask);
                float w1 = __shfl_xor(v1, mask); int j1 = __shfl_xor(i1, mask);
                top2_insert(w0, j0, v0, i0, v1, i1);
                top2_insert(w1, j1, v0, i0, v1, i1);
            }
            if ((lane & 15) == 0) {
                int row_local = waveM + m * 16 + (lane >> 4) * 4 + r;
                red4[row_local * 4 + wn] =
                    make_float4(v0, __int_as_float(i0), v1, __int_as_float(i1));
            }
        }
    }
    __syncthreads();
    if (tid < 256) {
        float4 p0 = red4[tid * 4 + 0];
        float v0 = p0.x, v1 = p0.z;
        int i0 = __float_as_int(p0.y), i1 = __float_as_int(p0.w);
        #pragma unroll
        for (int g = 1; g < 4; g++) {
            float4 p = red4[tid * 4 + g];
            top2_insert(p.x, __float_as_int(p.y), v0, i0, v1, i1);
            top2_insert(p.z, __float_as_int(p.w), v0, i0, v1, i1);
        }
        partial[(size_t)(rowBase + tid) * GX2 + bx] =
            make_float4(v0, __int_as_float(i0), v1, __int_as_float(i1));
    }
}

// ---------------------------------------------------------------------------
// Rescue: fp64 rescore of all candidates within MARGIN of approx global min.
// ---------------------------------------------------------------------------
__global__ __launch_bounds__(256) void rescore_kernel(const float* __restrict__ x,
                                                      const float* __restrict__ w,
                                                      const float4* __restrict__ partial,
                                                      float* __restrict__ out, int ng) {
    int wid = threadIdx.x >> 6, lane = threadIdx.x & 63;
    int row = blockIdx.x * 4 + wid;
    __shared__ int s_cnt[4];
    __shared__ int s_cand[4][64];

    const float4* part = partial + (size_t)row * ng;

    float bv = INFINITY;
    for (int c = lane; c < ng; c += 64) bv = fminf(bv, part[c].x);
    #pragma unroll
    for (int mask = 1; mask < 64; mask <<= 1) bv = fminf(bv, __shfl_xor(bv, mask));
    float thr = bv + MARGIN;

    if (lane == 0) s_cnt[wid] = 0;
    __syncthreads();
    for (int c = lane; c < ng; c += 64) {
        float4 p = part[c];
        if (p.x <= thr) {
            int pos = atomicAdd(&s_cnt[wid], 1);
            if (pos < 64) s_cand[wid][pos] = __float_as_int(p.y);
        }
        if (p.z <= thr) {
            int pos = atomicAdd(&s_cnt[wid], 1);
            if (pos < 64) s_cand[wid][pos] = __float_as_int(p.w);
        }
    }
    __syncthreads();
    int cnt = s_cnt[wid]; if (cnt > 64) cnt = 64;

    double bd = INFINITY; int bi = 0x7fffffff;
    for (int c = 0; c < cnt; c++) {
        int idx = s_cand[wid][c];
        const float* wr = w + (size_t)idx * D;
        const float* xr = x + (size_t)row * D;
        double s = 0.0;
        for (int d = lane; d < D; d += 64) {
            double wv = (double)wr[d];
            s += wv * (wv - 2.0 * (double)xr[d]);
        }
        #pragma unroll
        for (int mask = 1; mask < 64; mask <<= 1) s += __shfl_xor(s, mask);
        if (s < bd || (s == bd && idx < bi)) { bd = s; bi = idx; }
    }

    const float4* src = (const float4*)(w + (size_t)bi * D);
    float4* dst = (float4*)(out + (size_t)row * D);
    for (int i = lane; i < D / 4; i += 64) dst[i] = src[i];
}

// ---------------------------------------------------------------------------
extern "C" void kernel_launch(void* const* d_in, const int* in_sizes, int n_in,
                              void* d_out, int out_size, void* d_ws, size_t ws_size,
                              hipStream_t stream) {
    const float* x = (const float*)d_in[0];
    const float* w = (const float*)d_in[1];
    float* out = (float*)d_out;

    const size_t off_xh = 0;
    const size_t off_wh = off_xh + (size_t)BATCH * KP * 2;     // 6,553,600
    const size_t off_wsq = off_wh + (size_t)NPAD * KP * 2;     // +16,384,000
    const size_t off_part = off_wsq + (size_t)NPAD * 4;        // +40,960
    // need = off_part + 4096*40*16 = 25,600,000  (== round-7 proven footprint)

    unsigned short* xh = (unsigned short*)((char*)d_ws + off_xh);
    unsigned short* wh = (unsigned short*)((char*)d_ws + off_wh);
    float* wsq = (float*)((char*)d_ws + off_wsq);
    float4* partial = (float4*)((char*)d_ws + off_part);

    hipLaunchKernelGGL(convert_x_kernel, dim3(BATCH), dim3(256), 0, stream, x, xh);
    hipLaunchKernelGGL(convert_w_kernel, dim3(NPAD), dim3(256), 0, stream, w, wh, wsq);
    hipLaunchKernelGGL(dist_mfma256_kernel, dim3(GX2, GY2), dim3(512), 0, stream,
                       xh, wh, wsq, partial);
    hipLaunchKernelGGL(rescore_kernel, dim3(BATCH / 4), dim3(256), 0, stream,
                       x, w, partial, out, GX2);
}